// Round 10
// baseline (132.231 us; speedup 1.0000x reference)
//
#include <hip/hip_runtime.h>
#include <hip/hip_bf16.h>
#include <cstdint>
#include <math.h>

// Shapes: B=256, P=128, K=512, HE=1024, HF=512 (2HF=1024), D=2560, HID=64
// Outputs: embeddings (256,1,1536) then weights (256,128), fp32, flat-concat.
//
// R9: keys movement via __builtin_amdgcn_global_load_lds (async DMA, fp32 raw)
// in 16-row chunks, 4 LDS buffers, fine-grained `s_waitcnt vmcnt(8)` + raw
// s_barrier (never vmcnt(0) mid-pipeline). R8 post-mortem: compiler sinks all
// register-prefetch loads (VGPR=32!), serializing staging at 1 load/wave ->
// ~6 GB/s/CU. DMA has no VGPRs to sink.
// Ledger (attn µs): R2 39 | R3 44 | R5 95 | R6 65 | R7 42 | R8 42.5.
// Lessons: no inter-block coupling; vmcnt is one per-wave in-order queue;
// source-level reg pipelines are un-enforceable -> use global_load_lds.

typedef __bf16 bf16;
typedef __attribute__((ext_vector_type(8))) __bf16 bf16x8;
typedef __attribute__((ext_vector_type(4))) __bf16 bf16x4;
typedef __attribute__((ext_vector_type(4))) float f32x4;

#define NB 256
#define NP 128
#define NK 512
#define RSTR 516          // fp32 LDS row stride: 2064B, 16B-aligned, min-conflict
#define CHUNK_F (16 * RSTR)                 // floats per 16-row chunk buffer (8256)
#define BUF_BYTES (4 * CHUNK_F * 4)         // 132096
#define SQF_OFF   BUF_BYTES                 // bf16[2048] = 4096B
#define PP_OFF    (SQF_OFF + 4096)          // f32[8][64] = 2048B
#define PRP_OFF   (PP_OFF + 2048)           // f32[4][128] = 2048B
#define WTS_OFF   (PRP_OFF + 2048)          // f32[128] = 512B
#define W2_OFF    (WTS_OFF + 512)           // f32[64] = 256B
#define SMEM_BYTES (W2_OFF + 256)           // 141056 < 160K

__device__ __forceinline__ void async_copy16(const float* g, float* l) {
    __builtin_amdgcn_global_load_lds(
        (const __attribute__((address_space(1))) void*)g,
        (__attribute__((address_space(3))) void*)l, 16, 0, 0);
}

// ---------------- prep: weight repack only ----------------
// blocks 0..15 : w1kt[h][k]  = bf16(W1[k*64+h])
// blocks 16..79: w1qft[h][d] = bf16(W1[(512+d)*64+h])
__global__ __launch_bounds__(256) void prep_kernel(
    const float* __restrict__ W1, bf16* __restrict__ w1kt,
    bf16* __restrict__ w1qft)
{
    const int blk = blockIdx.x;
    const int t = threadIdx.x;
    __shared__ float s[32][65];
    if (blk < 16) {
        const int k0 = blk * 32;
#pragma unroll
        for (int i = 0; i < 8; i++) {
            const int idx = t + 256 * i;
            const int k = idx >> 6, h = idx & 63;
            s[k][h] = W1[(size_t)(k0 + k) * 64 + h];
        }
        __syncthreads();
#pragma unroll
        for (int i = 0; i < 8; i++) {
            const int idx = t + 256 * i;
            const int h = idx >> 5, kk = idx & 31;
            w1kt[(size_t)h * 512 + k0 + kk] = (bf16)s[kk][h];
        }
    } else {
        const int j = blk - 16;              // 0..63
        const int d0 = j * 32;
#pragma unroll
        for (int i = 0; i < 8; i++) {
            const int idx = t + 256 * i;
            const int r = idx >> 6, h = idx & 63;
            s[r][h] = W1[(size_t)(512 + d0 + r) * 64 + h];
        }
        __syncthreads();
#pragma unroll
        for (int i = 0; i < 8; i++) {
            const int idx = t + 256 * i;
            const int h = idx >> 5, rr = idx & 31;
            w1qft[(size_t)h * 2048 + d0 + rr] = (bf16)s[rr][h];
        }
    }
}

// ---------------- attn: fused, one block per batch, 8 waves, DMA pipeline ---
__global__ __launch_bounds__(512, 2) void attn_kernel(
    const float* __restrict__ keys, const float* __restrict__ query,
    const float* __restrict__ frame, const int* __restrict__ mask,
    const float* __restrict__ W2, const bf16* __restrict__ w1kt,
    const bf16* __restrict__ w1qft, float* __restrict__ out)
{
    extern __shared__ char smem[];
    float* buf    = (float*)smem;                  // [4][16][516] fp32 key chunks
    bf16*  sqf    = (bf16*)(smem + SQF_OFF);       // [2048] concat(query,frame)
    float* pp     = (float*)(smem + PP_OFF);       // [8][64] proj partials
    float* prp    = (float*)(smem + PRP_OFF);      // [4][128] score nt-partials
    float* wts    = (float*)(smem + WTS_OFF);      // [128]
    float* w2l    = (float*)(smem + W2_OFF);       // [64]

    const int b = blockIdx.x;
    const int t = threadIdx.x;
    const int w = t >> 6;          // wave 0..7
    const int lane = t & 63;
    const int m = lane & 15;
    const int q = lane >> 4;

    if (t < 64) w2l[t] = W2[t];

    // ---- stage qf (query+frame, 4KB) -> LDS bf16 ----
    {
        const float* qsrc = (t < 256 ? query : frame) + (size_t)b * 1024 + (t & 255) * 4;
        const float4 qv = *(const float4*)qsrc;
        bf16x4 qb;
        qb[0] = (bf16)qv.x; qb[1] = (bf16)qv.y; qb[2] = (bf16)qv.z; qb[3] = (bf16)qv.w;
        *(bf16x4*)(sqf + t * 4) = qb;
    }
    __syncthreads();

    // ---- phase P: proj partial for d-chunk [256w, 256w+256) via MFMA ----
    {
        const bf16* wb = w1qft + (size_t)m * 2048 + w * 256 + q * 8;
        f32x4 pacc[4];
#pragma unroll
        for (int nt = 0; nt < 4; nt++) pacc[nt] = (f32x4){0.f, 0.f, 0.f, 0.f};
        bf16x8 Bp[4];
#pragma unroll
        for (int nt = 0; nt < 4; nt++) Bp[nt] = *(const bf16x8*)(wb + nt * 32768);
#pragma unroll
        for (int kk = 0; kk < 8; kk++) {
            const bf16x8 Af = *(const bf16x8*)(sqf + w * 256 + kk * 32 + q * 8);
            bf16x8 Bc[4];
#pragma unroll
            for (int nt = 0; nt < 4; nt++) Bc[nt] = Bp[nt];
            if (kk < 7) {
#pragma unroll
                for (int nt = 0; nt < 4; nt++)
                    Bp[nt] = *(const bf16x8*)(wb + nt * 32768 + (kk + 1) * 32);
            }
#pragma unroll
            for (int nt = 0; nt < 4; nt++)
                pacc[nt] = __builtin_amdgcn_mfma_f32_16x16x32_bf16(Af, Bc[nt], pacc[nt], 0, 0, 0);
        }
        if (q == 0) {
#pragma unroll
            for (int nt = 0; nt < 4; nt++)
                pp[w * 64 + nt * 16 + m] = pacc[nt][0];
        }
    }
    __syncthreads();

    // ---- epilogue constants (waves 0..3 compute; wave w owns N-tile nt=w) ----
    const int nt = w & 3;
    const int h = nt * 16 + m;
    const float pv = pp[h] + pp[64 + h] + pp[128 + h] + pp[192 + h]
                   + pp[256 + h] + pp[320 + h] + pp[384 + h] + pp[448 + h];
    const float w2v = w2l[h];

    // B-fragments for this wave's nt (L2-hot; compiler may sink -> acceptable)
    bf16x8 Bv[16];
#pragma unroll
    for (int kk = 0; kk < 16; kk++)
        Bv[kk] = *(const bf16x8*)(w1kt + (size_t)(nt * 16 + m) * 512 + kk * 32 + q * 8);

    const float* kb = keys + (size_t)b * (NP * NK);

    // chunk c: keys rows [16c,16c+16) -> buf[c&3]; wave w DMAs rows 2w,2w+1
    auto issue_chunk = [&](int c) {
        const int cb = c & 3;
#pragma unroll
        for (int i = 0; i < 2; i++) {
            const int rl = 2 * w + i;
#pragma unroll
            for (int hh = 0; hh < 2; hh++)
                async_copy16(kb + (size_t)(16 * c + rl) * 512 + hh * 256 + lane * 4,
                             buf + (size_t)cb * CHUNK_F + rl * RSTR + hh * 256);
        }
    };

    // score compute for chunk c: MFMA over 16 rows, fold relu+W2, write prp
    auto compute_chunk = [&](int c) {
        const float* ab = buf + (size_t)(c & 3) * CHUNK_F + m * RSTR + q * 8;
        f32x4 acc = (f32x4){0.f, 0.f, 0.f, 0.f};
#pragma unroll
        for (int kk = 0; kk < 16; kk++) {
            const float4 fa = *(const float4*)(ab + kk * 32);
            const float4 fb = *(const float4*)(ab + kk * 32 + 4);
            bf16x8 Af;
            Af[0] = (bf16)fa.x; Af[1] = (bf16)fa.y; Af[2] = (bf16)fa.z; Af[3] = (bf16)fa.w;
            Af[4] = (bf16)fb.x; Af[5] = (bf16)fb.y; Af[6] = (bf16)fb.z; Af[7] = (bf16)fb.w;
            acc = __builtin_amdgcn_mfma_f32_16x16x32_bf16(Af, Bv[kk], acc, 0, 0, 0);
        }
        float pr[4];
#pragma unroll
        for (int r = 0; r < 4; r++) pr[r] = fmaxf(acc[r] + pv, 0.f) * w2v;
#pragma unroll
        for (int off = 1; off < 16; off <<= 1) {
#pragma unroll
            for (int r = 0; r < 4; r++) pr[r] += __shfl_xor(pr[r], off);
        }
        if (m == 0) {
#pragma unroll
            for (int r = 0; r < 4; r++)
                prp[nt * 128 + 16 * c + q * 4 + r] = pr[r];
        }
    };

    // ---- score pipeline: 3 chunks in flight, vmcnt(8) = wait oldest chunk ----
    issue_chunk(0); issue_chunk(1); issue_chunk(2);
#define STEP(c, WSTR) \
    asm volatile(WSTR "\ns_barrier" ::: "memory"); \
    if ((c) + 3 < 8) issue_chunk((c) + 3); \
    if (w < 4) compute_chunk(c);
    STEP(0, "s_waitcnt vmcnt(8)")
    STEP(1, "s_waitcnt vmcnt(8)")
    STEP(2, "s_waitcnt vmcnt(8)")
    STEP(3, "s_waitcnt vmcnt(8)")
    STEP(4, "s_waitcnt vmcnt(8)")
    STEP(5, "s_waitcnt vmcnt(8)")
    STEP(6, "s_waitcnt vmcnt(4)")
    STEP(7, "s_waitcnt vmcnt(0)")
#undef STEP
    __syncthreads();

    // ---- masked softmax over 128 scores (wave 0), write weights ----
    if (w == 0) {
        const int pa = lane, pb = lane + 64;
        float s0 = prp[pa] + prp[128 + pa] + prp[256 + pa] + prp[384 + pa];
        float s1 = prp[pb] + prp[128 + pb] + prp[256 + pb] + prp[384 + pb];
        s0 = (mask[b * 128 + pa] == 0) ? -INFINITY : s0;
        s1 = (mask[b * 128 + pb] == 0) ? -INFINITY : s1;
        float mx = fmaxf(s0, s1);
#pragma unroll
        for (int off = 32; off; off >>= 1) mx = fmaxf(mx, __shfl_xor(mx, off));
        float e0 = __expf(s0 - mx), e1 = __expf(s1 - mx);
        float sum = e0 + e1;
#pragma unroll
        for (int off = 32; off; off >>= 1) sum += __shfl_xor(sum, off);
        const float inv = 1.0f / sum;
        e0 *= inv; e1 *= inv;
        wts[pa] = e0; wts[pb] = e1;
        float* wout = out + (size_t)NB * 1536;
        wout[b * 128 + pa] = e0;
        wout[b * 128 + pb] = e1;
    }
    __syncthreads();

    // ---- context[col t] = sum_p wts[p]*keys[p][t], fp32 ----
    float ca = 0.f, cb2 = 0.f;
    // part 1: chunks 4..7 still resident in buf 0..3 (rows 64..127)
#pragma unroll
    for (int bi = 0; bi < 4; bi++) {
#pragma unroll
        for (int i = 0; i < 16; i += 2) {
            ca  += wts[64 + bi * 16 + i]     * buf[(size_t)bi * CHUNK_F + i * RSTR + t];
            cb2 += wts[64 + bi * 16 + i + 1] * buf[(size_t)bi * CHUNK_F + (i + 1) * RSTR + t];
        }
    }
    __syncthreads();   // all reads of resident chunks done before re-DMA

    // part 2: re-DMA chunks 0..3 (L2/L3-hot) with same pipeline
    issue_chunk(0); issue_chunk(1); issue_chunk(2);
#define CSTEP(j, WSTR) \
    asm volatile(WSTR "\ns_barrier" ::: "memory"); \
    if ((j) + 3 < 4) issue_chunk((j) + 3); \
    _Pragma("unroll") \
    for (int i = 0; i < 16; i += 2) { \
        ca  += wts[(j) * 16 + i]     * buf[(size_t)((j) & 3) * CHUNK_F + i * RSTR + t]; \
        cb2 += wts[(j) * 16 + i + 1] * buf[(size_t)((j) & 3) * CHUNK_F + (i + 1) * RSTR + t]; \
    }
    CSTEP(0, "s_waitcnt vmcnt(8)")
    CSTEP(1, "s_waitcnt vmcnt(8)")
    CSTEP(2, "s_waitcnt vmcnt(4)")
    CSTEP(3, "s_waitcnt vmcnt(0)")
#undef CSTEP
    out[(size_t)b * 1536 + t] = ca + cb2;

    // ---- frame passthrough: embeddings[:, 512:1536] = frameLSTM_h ----
    {
        const float2 fv = *(const float2*)(frame + (size_t)b * 1024 + t * 2);
        *(float2*)(out + (size_t)b * 1536 + 512 + t * 2) = fv;
    }
}

extern "C" void kernel_launch(void* const* d_in, const int* in_sizes, int n_in,
                              void* d_out, int out_size, void* d_ws, size_t ws_size,
                              hipStream_t stream) {
    const float* query = (const float*)d_in[0];
    const float* keys  = (const float*)d_in[1];
    const float* frame = (const float*)d_in[2];
    const int*   mask  = (const int*)d_in[3];
    const float* W1    = (const float*)d_in[4];
    const float* W2    = (const float*)d_in[5];
    float* out = (float*)d_out;

    // ws: [0,64K) w1kt bf16 [64][512]; [64K,320K) w1qft bf16 [64][2048]
    bf16* w1kt  = (bf16*)d_ws;
    bf16* w1qft = (bf16*)((char*)d_ws + (64 << 10));

    hipFuncSetAttribute((const void*)attn_kernel,
                        hipFuncAttributeMaxDynamicSharedMemorySize, SMEM_BYTES);

    prep_kernel<<<80, 256, 0, stream>>>(W1, w1kt, w1qft);
    attn_kernel<<<256, 512, SMEM_BYTES, stream>>>(keys, query, frame, mask, W2,
                                                  w1kt, w1qft, out);
}